// Round 2
// baseline (5281.471 us; speedup 1.0000x reference)
//
#include <hip/hip_runtime.h>
#include <math.h>

#define NFULL 2177   // 1 + L + S
#define NN    2176   // minor size, = 34*64
#define NMAT  8      // 4 batches x {z, target}
#define NBATCH 4

// ---------------- build phase ----------------

__global__ void init_cs_kernel(float* __restrict__ cs) {
  int i = blockIdx.x * blockDim.x + threadIdx.x;
  if (i < NMAT * NN) cs[i] = 0.f;
}

// Fused build: M off-diag = -w for both masks, column sums via register
// partials + one atomicAdd per thread per mask. Rows r=0..NN-1 are minor rows
// (node i=r+1); node row 0's colsum contribution is added in diag_fix.
__global__ __launch_bounds__(256) void build_kernel(
    const float* __restrict__ scores, const float* __restrict__ zm,
    const float* __restrict__ tm, const int* __restrict__ lengths,
    float* __restrict__ M, float* __restrict__ cs) {
  int c = blockIdx.x * 256 + threadIdx.x;
  if (c >= NN) return;
  int b = blockIdx.z;
  int len = lengths[b];
  int j = c + 1;
  bool jv = (j < len);
  int r0 = blockIdx.y * 16;
  size_t sbase = (size_t)b * NFULL * NFULL;
  float* Mz = M + (size_t)b * NN * NN;
  float* Mt = M + (size_t)(NBATCH + b) * NN * NN;
  float az = 0.f, at = 0.f;
  for (int rr = 0; rr < 16; ++rr) {
    int r = r0 + rr, i = r + 1;
    float vz = 0.f, vt = 0.f;
    if (jv && i < len) {
      size_t off = sbase + (size_t)i * NFULL + j;
      float e = __expf(scores[off]);
      vz = e * zm[off];
      vt = e * tm[off];
    }
    Mz[(size_t)r * NN + c] = -vz;
    Mt[(size_t)r * NN + c] = -vt;
    az += vz; at += vt;
  }
  atomicAdd(&cs[b * NN + c], az);
  atomicAdd(&cs[(NBATCH + b) * NN + c], at);
}

// diag = colsum + w[0][j] + pad   (pad=1 on invalid nodes -> unit pivot)
__global__ void diag_fix_kernel(const float* __restrict__ scores,
                                const float* __restrict__ zm,
                                const float* __restrict__ tm,
                                const int* __restrict__ lengths,
                                const float* __restrict__ cs,
                                float* __restrict__ M) {
  int c = blockIdx.x * 256 + threadIdx.x;
  if (c >= NN) return;
  int m = blockIdx.y;
  int b = m & 3;
  const float* msk = (m < NBATCH) ? zm : tm;
  int len = lengths[b];
  int j = c + 1;
  float w0 = 0.f, pad = 1.f;
  if (j < len) {
    size_t off = (size_t)b * NFULL * NFULL + j;  // row 0
    w0 = __expf(scores[off]) * msk[off];
    pad = 0.f;
  }
  M[(size_t)m * NN * NN + (size_t)c * NN + c] = cs[m * NN + c] + w0 + pad;
}

// ---------------- LU helpers ----------------

// factor 64x64 (stride-65 LDS) in place, 256 threads; L unit-lower \ U upper
__device__ inline void factor64_lds(float* D, int tid) {
  for (int j = 0; j < 63; ++j) {
    float inv = 1.0f / D[j * 65 + j];
    for (int r = j + 1 + tid; r < 64; r += 256) D[r * 65 + j] *= inv;
    __syncthreads();
    int cc = j + 1 + (tid & 63);
    for (int rr = j + 1 + (tid >> 6); rr < 64; rr += 4) {
      if (cc < 64) D[rr * 65 + cc] -= D[rr * 65 + j] * D[j * 65 + cc];
    }
    __syncthreads();
  }
}

__global__ __launch_bounds__(256) void factor_diag(float* __restrict__ Mb, int k0) {
  __shared__ float D[64 * 65];
  int m = blockIdx.x;
  float* A = Mb + (size_t)m * NN * NN;
  int tid = threadIdx.x;
  for (int idx = tid; idx < 64 * 64; idx += 256) {
    int r = idx >> 6, c = idx & 63;
    D[r * 65 + c] = A[(size_t)(k0 + r) * NN + k0 + c];
  }
  __syncthreads();
  factor64_lds(D, tid);
  for (int idx = tid; idx < 64 * 64; idx += 256) {
    int r = idx >> 6, c = idx & 63;
    A[(size_t)(k0 + r) * NN + k0 + c] = D[r * 65 + c];
  }
}

// fused L21 (role 0) / U12 (role 1) solves; 128 threads, 2 tiles per block,
// no barriers inside the solve (each thread owns a full row / column).
__global__ __launch_bounds__(128) void panel_solve(float* __restrict__ Mb, int k0) {
  __shared__ float D[64 * 65];
  __shared__ float invD[64];
  __shared__ float T[128 * 67];  // role1 reuses as [64][130]
  int m = blockIdx.y, role = blockIdx.z;
  float* A = Mb + (size_t)m * NN * NN;
  int tid = threadIdx.x;
  int rem = NN - k0 - 64;
  int sbase = blockIdx.x * 128;
  for (int idx = tid; idx < 64 * 64; idx += 128) {
    int r = idx >> 6, c = idx & 63;
    D[r * 65 + c] = A[(size_t)(k0 + r) * NN + k0 + c];
  }
  __syncthreads();
  if (tid < 64) invD[tid] = 1.0f / D[tid * 65 + tid];
  if (role == 0) {
    int nrow = rem - sbase; if (nrow > 128) nrow = 128;
    for (int idx = tid; idx < 128 * 64; idx += 128) {
      int r = idx >> 6, c = idx & 63;
      if (r < nrow) T[r * 67 + c] = A[(size_t)(k0 + 64 + sbase + r) * NN + k0 + c];
    }
    __syncthreads();
    if (tid < nrow) {
      float* Tr = &T[tid * 67];
      for (int j = 0; j < 64; ++j) {
        float acc = Tr[j];
        for (int t = 0; t < j; ++t) acc -= Tr[t] * D[t * 65 + j];
        Tr[j] = acc * invD[j];
      }
    }
    __syncthreads();
    for (int idx = tid; idx < 128 * 64; idx += 128) {
      int r = idx >> 6, c = idx & 63;
      if (r < nrow) A[(size_t)(k0 + 64 + sbase + r) * NN + k0 + c] = T[r * 67 + c];
    }
  } else {
    int ncol = rem - sbase; if (ncol > 128) ncol = 128;
    for (int idx = tid; idx < 64 * 128; idx += 128) {
      int r = idx >> 7, c = idx & 127;
      if (c < ncol) T[r * 130 + c] = A[(size_t)(k0 + r) * NN + k0 + 64 + sbase + c];
    }
    __syncthreads();
    if (tid < ncol) {
      for (int j = 1; j < 64; ++j) {
        float acc = T[j * 130 + tid];
        for (int t = 0; t < j; ++t) acc -= D[j * 65 + t] * T[t * 130 + tid];
        T[j * 130 + tid] = acc;
      }
    }
    __syncthreads();
    for (int idx = tid; idx < 64 * 128; idx += 128) {
      int r = idx >> 7, c = idx & 127;
      if (c < ncol) A[(size_t)(k0 + r) * NN + k0 + 64 + sbase + c] = T[r * 130 + c];
    }
  }
}

// trailing update A22 -= L21*U12: 128x128 tile, 8x8 microtile (split 4+4 at
// +64), K=64. Block (0,0) then factors the next 64x64 diagonal block in LDS.
__global__ __launch_bounds__(256) void trail_gemm(float* __restrict__ Mb, int k0) {
  __shared__ float La[128 * 64];  // [r][k], k-chunks XOR-swizzled by (r>>2)&3
  __shared__ float Ub[64 * 128];  // [k][c]
  int m = blockIdx.z;
  float* A = Mb + (size_t)m * NN * NN;
  int base = k0 + 64;
  int rbase = base + blockIdx.y * 128;
  int cbase = base + blockIdx.x * 128;
  int tid = threadIdx.x;
#pragma unroll
  for (int it = 0; it < 8; ++it) {
    int idx = tid + it * 256;
    int r = idx >> 4, k4 = idx & 15;
    int gr = rbase + r; if (gr >= NN) gr = NN - 1;
    float4 v = *(const float4*)&A[(size_t)gr * NN + k0 + k4 * 4];
    int sw = (k4 ^ ((r >> 2) & 3)) * 4;
    *(float4*)&La[r * 64 + sw] = v;
  }
#pragma unroll
  for (int it = 0; it < 8; ++it) {
    int idx = tid + it * 256;
    int k = idx >> 5, c4 = idx & 31;
    int gc = cbase + c4 * 4;
    float4 v = make_float4(0.f, 0.f, 0.f, 0.f);
    if (gc + 3 < NN) v = *(const float4*)&A[(size_t)(k0 + k) * NN + gc];
    *(float4*)&Ub[k * 128 + c4 * 4] = v;
  }
  __syncthreads();
  int r0 = (tid >> 4) * 4;
  int c0 = (tid & 15) * 4;
  float acc[8][8];
#pragma unroll
  for (int i = 0; i < 8; ++i)
#pragma unroll
    for (int jj = 0; jj < 8; ++jj) acc[i][jj] = 0.f;
#pragma unroll 2
  for (int kc = 0; kc < 16; ++kc) {
    float4 av[8], bv[8];
#pragma unroll
    for (int i = 0; i < 4; ++i) {
      int r = r0 + i;
      int sw = (kc ^ ((r >> 2) & 3)) * 4;
      av[i]     = *(const float4*)&La[r * 64 + sw];
      av[4 + i] = *(const float4*)&La[(r + 64) * 64 + sw];  // same swizzle class
    }
#pragma unroll
    for (int kk = 0; kk < 4; ++kk) {
      bv[2 * kk]     = *(const float4*)&Ub[(kc * 4 + kk) * 128 + c0];
      bv[2 * kk + 1] = *(const float4*)&Ub[(kc * 4 + kk) * 128 + c0 + 64];
    }
#pragma unroll
    for (int kk = 0; kk < 4; ++kk) {
      float bc[8];
      bc[0] = ((const float*)&bv[2 * kk])[0];     bc[1] = ((const float*)&bv[2 * kk])[1];
      bc[2] = ((const float*)&bv[2 * kk])[2];     bc[3] = ((const float*)&bv[2 * kk])[3];
      bc[4] = ((const float*)&bv[2 * kk + 1])[0]; bc[5] = ((const float*)&bv[2 * kk + 1])[1];
      bc[6] = ((const float*)&bv[2 * kk + 1])[2]; bc[7] = ((const float*)&bv[2 * kk + 1])[3];
#pragma unroll
      for (int i = 0; i < 8; ++i) {
        float aval = ((const float*)&av[i])[kk];
#pragma unroll
        for (int jj = 0; jj < 8; ++jj) acc[i][jj] += aval * bc[jj];
      }
    }
  }
  // C RMW (guards only matter when rem%128==64 edge tiles overhang)
#pragma unroll
  for (int i = 0; i < 8; ++i) {
    int row = rbase + r0 + (i < 4 ? i : 60 + i);
    if (row < NN) {
#pragma unroll
      for (int h = 0; h < 2; ++h) {
        int col = cbase + c0 + h * 64;
        if (col < NN) {
          float4* p = (float4*)&A[(size_t)row * NN + col];
          float4 v = *p;
          v.x -= acc[i][h * 4 + 0]; v.y -= acc[i][h * 4 + 1];
          v.z -= acc[i][h * 4 + 2]; v.w -= acc[i][h * 4 + 3];
          *p = v;
        }
      }
    }
  }
  // fused factor of next diagonal block (corner of trailing matrix)
  if (blockIdx.x == 0 && blockIdx.y == 0) {
    __syncthreads();  // drain this block's C stores; corner written only by this block
    float* D = La;    // reuse (needs 64*65 <= 128*64)
    for (int idx = tid; idx < 64 * 64; idx += 256) {
      int r = idx >> 6, c = idx & 63;
      D[r * 65 + c] = A[(size_t)(base + r) * NN + base + c];
    }
    __syncthreads();
    factor64_lds(D, tid);
    for (int idx = tid; idx < 64 * 64; idx += 256) {
      int r = idx >> 6, c = idx & 63;
      A[(size_t)(base + r) * NN + base + c] = D[r * 65 + c];
    }
  }
}

// ---------------- reduction ----------------

__global__ void logdet_kernel(const float* __restrict__ Mb, double* __restrict__ dlog) {
  int m = blockIdx.x;
  const float* A = Mb + (size_t)m * NN * NN;
  double s = 0.0;
  for (int i = threadIdx.x; i < NN; i += 256)
    s += (double)logf(fabsf(A[(size_t)i * NN + i]));
  __shared__ double red[256];
  red[threadIdx.x] = s;
  __syncthreads();
  for (int k = 128; k > 0; k >>= 1) {
    if (threadIdx.x < k) red[threadIdx.x] += red[threadIdx.x + k];
    __syncthreads();
  }
  if (threadIdx.x == 0) dlog[m] = red[0];
}

__global__ void final_kernel(const double* __restrict__ dlog, float* __restrict__ out) {
  if (threadIdx.x == 0) {
    double acc = 0.0;
    for (int b = 0; b < NBATCH; ++b) acc += dlog[b] - dlog[NBATCH + b];
    out[0] = (float)(acc * 0.25);
  }
}

// ---------------- launch ----------------

extern "C" void kernel_launch(void* const* d_in, const int* in_sizes, int n_in,
                              void* d_out, int out_size, void* d_ws, size_t ws_size,
                              hipStream_t stream) {
  const float* scores  = (const float*)d_in[0];
  const float* tm      = (const float*)d_in[1];
  const float* zm      = (const float*)d_in[2];
  const int*   lengths = (const int*)d_in[3];
  float* out = (float*)d_out;

  float* M  = (float*)d_ws;                       // 8 * 2176^2 f32
  float* cs = M + (size_t)NMAT * NN * NN;         // 8 * 2176 f32
  double* dlog = (double*)(cs + (size_t)NMAT * NN);

  init_cs_kernel<<<(NMAT * NN + 255) / 256, 256, 0, stream>>>(cs);
  build_kernel<<<dim3((NN + 255) / 256, NN / 16, NBATCH), 256, 0, stream>>>(
      scores, zm, tm, lengths, M, cs);
  diag_fix_kernel<<<dim3((NN + 255) / 256, NMAT), 256, 0, stream>>>(
      scores, zm, tm, lengths, cs, M);
  factor_diag<<<NMAT, 256, 0, stream>>>(M, 0);

  for (int k0 = 0; k0 < NN - 64; k0 += 64) {
    int rem = NN - k0 - 64;
    int nt = (rem + 127) / 128;
    panel_solve<<<dim3(nt, NMAT, 2), 128, 0, stream>>>(M, k0);
    trail_gemm<<<dim3(nt, nt, NMAT), 256, 0, stream>>>(M, k0);
  }

  logdet_kernel<<<NMAT, 256, 0, stream>>>(M, dlog);
  final_kernel<<<1, 64, 0, stream>>>(dlog, out);
}

// Round 3
// 4700.851 us; speedup vs baseline: 1.1235x; 1.1235x over previous
//
#include <hip/hip_runtime.h>
#include <math.h>

#define NFULL 2177   // 1 + L + S
#define NN    2176   // minor size, = 34*64 = 68*32
#define NMAT  8      // 4 batches x {z, target}
#define NBATCH 4
#define PFRAG (68 * 4 * 64 * 8)   // shorts per matrix per plane (68 row-tiles x 4 ksteps x 64 lanes x 8)

typedef unsigned int  u32;
typedef unsigned short u16;
typedef __attribute__((ext_vector_type(8)))  short short8;
typedef __attribute__((ext_vector_type(16))) float f32x16;

// split fp32 into bf16 hi + bf16 lo (round-nearest-even both)
__device__ inline void bf16split(float x, u16& hi, u16& lo) {
  u32 xb = __float_as_uint(x);
  u32 h = (xb + 0x7FFFu + ((xb >> 16) & 1u)) >> 16;
  float r = x - __uint_as_float(h << 16);
  u32 rb = __float_as_uint(r);
  u32 l = (rb + 0x7FFFu + ((rb >> 16) & 1u)) >> 16;
  hi = (u16)h; lo = (u16)l;
}

// ---------------- build phase ----------------

__global__ void init_cs_kernel(float* __restrict__ cs) {
  int i = blockIdx.x * blockDim.x + threadIdx.x;
  if (i < NMAT * NN) cs[i] = 0.f;
}

__global__ __launch_bounds__(256) void build_kernel(
    const float* __restrict__ scores, const float* __restrict__ zm,
    const float* __restrict__ tm, const int* __restrict__ lengths,
    float* __restrict__ M, float* __restrict__ cs) {
  int c = blockIdx.x * 256 + threadIdx.x;
  if (c >= NN) return;
  int b = blockIdx.z;
  int len = lengths[b];
  int j = c + 1;
  bool jv = (j < len);
  int r0 = blockIdx.y * 16;
  size_t sbase = (size_t)b * NFULL * NFULL;
  float* Mz = M + (size_t)b * NN * NN;
  float* Mt = M + (size_t)(NBATCH + b) * NN * NN;
  float az = 0.f, at = 0.f;
  for (int rr = 0; rr < 16; ++rr) {
    int r = r0 + rr, i = r + 1;
    float vz = 0.f, vt = 0.f;
    if (jv && i < len) {
      size_t off = sbase + (size_t)i * NFULL + j;
      float e = __expf(scores[off]);
      vz = e * zm[off];
      vt = e * tm[off];
    }
    Mz[(size_t)r * NN + c] = -vz;
    Mt[(size_t)r * NN + c] = -vt;
    az += vz; at += vt;
  }
  atomicAdd(&cs[b * NN + c], az);
  atomicAdd(&cs[(NBATCH + b) * NN + c], at);
}

__global__ void diag_fix_kernel(const float* __restrict__ scores,
                                const float* __restrict__ zm,
                                const float* __restrict__ tm,
                                const int* __restrict__ lengths,
                                const float* __restrict__ cs,
                                float* __restrict__ M) {
  int c = blockIdx.x * 256 + threadIdx.x;
  if (c >= NN) return;
  int m = blockIdx.y;
  int b = m & 3;
  const float* msk = (m < NBATCH) ? zm : tm;
  int len = lengths[b];
  int j = c + 1;
  float w0 = 0.f, pad = 1.f;
  if (j < len) {
    size_t off = (size_t)b * NFULL * NFULL + j;  // row 0 of full matrix
    w0 = __expf(scores[off]) * msk[off];
    pad = 0.f;
  }
  M[(size_t)m * NN * NN + (size_t)c * NN + c] = cs[m * NN + c] + w0 + pad;
}

// ---------------- LU helpers ----------------

__device__ inline void factor64_lds(float* D, int tid) {
  for (int j = 0; j < 63; ++j) {
    float inv = 1.0f / D[j * 65 + j];
    for (int r = j + 1 + tid; r < 64; r += 256) D[r * 65 + j] *= inv;
    __syncthreads();
    int cc = j + 1 + (tid & 63);
    for (int rr = j + 1 + (tid >> 6); rr < 64; rr += 4) {
      if (cc < 64) D[rr * 65 + cc] -= D[rr * 65 + j] * D[j * 65 + cc];
    }
    __syncthreads();
  }
}

__global__ __launch_bounds__(256) void factor_diag(float* __restrict__ Mb, int k0) {
  __shared__ float D[64 * 65];
  int m = blockIdx.x;
  float* A = Mb + (size_t)m * NN * NN;
  int tid = threadIdx.x;
  for (int idx = tid; idx < 64 * 64; idx += 256) {
    int r = idx >> 6, c = idx & 63;
    D[r * 65 + c] = A[(size_t)(k0 + r) * NN + k0 + c];
  }
  __syncthreads();
  factor64_lds(D, tid);
  for (int idx = tid; idx < 64 * 64; idx += 256) {
    int r = idx >> 6, c = idx & 63;
    A[(size_t)(k0 + r) * NN + k0 + c] = D[r * 65 + c];
  }
}

// panel solves: role 0 -> L21 rows, role 1 -> U12 cols. Output goes ONLY to the
// bf16 hi/lo fragment-layout panels (fp32 L21/U12 never needed again).
// Fragment layout (matches MFMA 32x32x16 A/B operand): chunk q = ((t*4+s)*64+l),
// 8 shorts at q*8; A: row=t*32+(l&31), k=s*16+(l>>5)*8+j; B: col=t*32+(l&31), same k.
__global__ __launch_bounds__(128) void panel_solve(
    float* __restrict__ Mb, short* __restrict__ Ahi, short* __restrict__ Alo,
    short* __restrict__ Bhi, short* __restrict__ Blo, int k0) {
  __shared__ float D[64 * 65];
  __shared__ float invD[64];
  __shared__ float T[128 * 67];  // role1 reuses as [64][130] (8320 <= 8576)
  int m = blockIdx.y, role = blockIdx.z;
  float* A = Mb + (size_t)m * NN * NN;
  size_t pb = (size_t)m * PFRAG;
  int tid = threadIdx.x;
  int rem = NN - k0 - 64;
  int sbase = blockIdx.x * 128;
  int tbase = sbase >> 5;
  for (int idx = tid; idx < 64 * 64; idx += 128) {
    int r = idx >> 6, c = idx & 63;
    D[r * 65 + c] = A[(size_t)(k0 + r) * NN + k0 + c];
  }
  __syncthreads();
  if (tid < 64) invD[tid] = 1.0f / D[tid * 65 + tid];
  if (role == 0) {
    int nrow = rem - sbase; if (nrow > 128) nrow = 128;   // multiple of 64
    for (int idx = tid; idx < 128 * 64; idx += 128) {
      int r = idx >> 6, c = idx & 63;
      if (r < nrow) T[r * 67 + c] = A[(size_t)(k0 + 64 + sbase + r) * NN + k0 + c];
    }
    __syncthreads();
    if (tid < nrow) {
      float* Tr = &T[tid * 67];
      for (int j = 0; j < 64; ++j) {
        float acc = Tr[j];
        for (int t = 0; t < j; ++t) acc -= Tr[t] * D[t * 65 + j];
        Tr[j] = acc * invD[j];
      }
    }
    __syncthreads();
    for (int f = tid; f < 1024; f += 128) {
      int tloc = f >> 8, s = (f >> 6) & 3, l = f & 63;
      if (tloc * 32 >= nrow) continue;
      int row = tloc * 32 + (l & 31);
      int kk = s * 16 + (l >> 5) * 8;
      u16 hi[8], lo[8];
#pragma unroll
      for (int j = 0; j < 8; ++j) bf16split(T[row * 67 + kk + j], hi[j], lo[j]);
      size_t off = pb + ((size_t)((tbase + tloc) * 4 + s) * 64 + l) * 8;
      *(uint4*)(Ahi + off) = make_uint4(hi[0] | ((u32)hi[1] << 16), hi[2] | ((u32)hi[3] << 16),
                                        hi[4] | ((u32)hi[5] << 16), hi[6] | ((u32)hi[7] << 16));
      *(uint4*)(Alo + off) = make_uint4(lo[0] | ((u32)lo[1] << 16), lo[2] | ((u32)lo[3] << 16),
                                        lo[4] | ((u32)lo[5] << 16), lo[6] | ((u32)lo[7] << 16));
    }
  } else {
    int ncol = rem - sbase; if (ncol > 128) ncol = 128;
    for (int idx = tid; idx < 64 * 128; idx += 128) {
      int r = idx >> 7, c = idx & 127;
      if (c < ncol) T[r * 130 + c] = A[(size_t)(k0 + r) * NN + k0 + 64 + sbase + c];
    }
    __syncthreads();
    if (tid < ncol) {
      for (int j = 1; j < 64; ++j) {
        float acc = T[j * 130 + tid];
        for (int t = 0; t < j; ++t) acc -= D[j * 65 + t] * T[t * 130 + tid];
        T[j * 130 + tid] = acc;
      }
    }
    __syncthreads();
    for (int f = tid; f < 1024; f += 128) {
      int ctloc = f >> 8, s = (f >> 6) & 3, l = f & 63;
      if (ctloc * 32 >= ncol) continue;
      int col = ctloc * 32 + (l & 31);
      int kk = s * 16 + (l >> 5) * 8;
      u16 hi[8], lo[8];
#pragma unroll
      for (int j = 0; j < 8; ++j) bf16split(T[(kk + j) * 130 + col], hi[j], lo[j]);
      size_t off = pb + ((size_t)((tbase + ctloc) * 4 + s) * 64 + l) * 8;
      *(uint4*)(Bhi + off) = make_uint4(hi[0] | ((u32)hi[1] << 16), hi[2] | ((u32)hi[3] << 16),
                                        hi[4] | ((u32)hi[5] << 16), hi[6] | ((u32)hi[7] << 16));
      *(uint4*)(Blo + off) = make_uint4(lo[0] | ((u32)lo[1] << 16), lo[2] | ((u32)lo[3] << 16),
                                        lo[4] | ((u32)lo[5] << 16), lo[6] | ((u32)lo[7] << 16));
    }
  }
}

__device__ inline void rmw_tile(float* __restrict__ A, int R0, int C0, const f32x16& ac) {
#pragma unroll
  for (int reg = 0; reg < 16; ++reg) {
    int row = R0 + (reg & 3) + 8 * (reg >> 2);
    A[(size_t)row * NN + C0] -= ac[reg];
  }
}

// trailing update A22 -= L21*U12 via split-bf16 MFMA (3 mfma per tile-k).
// 128x128 C per block, 4 waves, each wave 2x2 tiles of 32x32, K=64.
// Operands loaded as pre-swizzled fragments from global (no LDS).
// Block (0,0) then factors the next 64x64 diagonal block.
__global__ __launch_bounds__(256) void trail_gemm(
    float* __restrict__ Mb, const short* __restrict__ Ahi, const short* __restrict__ Alo,
    const short* __restrict__ Bhi, const short* __restrict__ Blo, int k0) {
  __shared__ float Dsh[64 * 65];
  int m = blockIdx.z;
  float* A = Mb + (size_t)m * NN * NN;
  size_t pb = (size_t)m * PFRAG;
  int tid = threadIdx.x;
  int w = tid >> 6, l = tid & 63;
  int wr = w >> 1, wc = w & 1;
  int rem = NN - k0 - 64;
  int rt0 = blockIdx.y * 4 + wr * 2;
  int ct0 = blockIdx.x * 4 + wc * 2;
  bool rv0 = rt0 * 32 < rem, rv1 = (rt0 + 1) * 32 < rem;
  bool cv0 = ct0 * 32 < rem, cv1 = (ct0 + 1) * 32 < rem;
  f32x16 a00, a01, a10, a11;
  for (int i = 0; i < 16; ++i) { a00[i] = 0.f; a01[i] = 0.f; a10[i] = 0.f; a11[i] = 0.f; }
  short8 zer;
  for (int i = 0; i < 8; ++i) zer[i] = 0;
#pragma unroll
  for (int s = 0; s < 4; ++s) {
    size_t qa0 = pb + ((size_t)(rt0 * 4 + s) * 64 + l) * 8;
    size_t qa1 = pb + ((size_t)((rt0 + 1) * 4 + s) * 64 + l) * 8;
    size_t qb0 = pb + ((size_t)(ct0 * 4 + s) * 64 + l) * 8;
    size_t qb1 = pb + ((size_t)((ct0 + 1) * 4 + s) * 64 + l) * 8;
    short8 ah0 = zer, al0 = zer, ah1 = zer, al1 = zer;
    short8 bh0 = zer, bl0 = zer, bh1 = zer, bl1 = zer;
    if (rv0) { ah0 = *(const short8*)(Ahi + qa0); al0 = *(const short8*)(Alo + qa0); }
    if (rv1) { ah1 = *(const short8*)(Ahi + qa1); al1 = *(const short8*)(Alo + qa1); }
    if (cv0) { bh0 = *(const short8*)(Bhi + qb0); bl0 = *(const short8*)(Blo + qb0); }
    if (cv1) { bh1 = *(const short8*)(Bhi + qb1); bl1 = *(const short8*)(Blo + qb1); }
    if (rv0 && cv0) {
      a00 = __builtin_amdgcn_mfma_f32_32x32x16_bf16(ah0, bh0, a00, 0, 0, 0);
      a00 = __builtin_amdgcn_mfma_f32_32x32x16_bf16(ah0, bl0, a00, 0, 0, 0);
      a00 = __builtin_amdgcn_mfma_f32_32x32x16_bf16(al0, bh0, a00, 0, 0, 0);
    }
    if (rv0 && cv1) {
      a01 = __builtin_amdgcn_mfma_f32_32x32x16_bf16(ah0, bh1, a01, 0, 0, 0);
      a01 = __builtin_amdgcn_mfma_f32_32x32x16_bf16(ah0, bl1, a01, 0, 0, 0);
      a01 = __builtin_amdgcn_mfma_f32_32x32x16_bf16(al0, bh1, a01, 0, 0, 0);
    }
    if (rv1 && cv0) {
      a10 = __builtin_amdgcn_mfma_f32_32x32x16_bf16(ah1, bh0, a10, 0, 0, 0);
      a10 = __builtin_amdgcn_mfma_f32_32x32x16_bf16(ah1, bl0, a10, 0, 0, 0);
      a10 = __builtin_amdgcn_mfma_f32_32x32x16_bf16(al1, bh0, a10, 0, 0, 0);
    }
    if (rv1 && cv1) {
      a11 = __builtin_amdgcn_mfma_f32_32x32x16_bf16(ah1, bh1, a11, 0, 0, 0);
      a11 = __builtin_amdgcn_mfma_f32_32x32x16_bf16(ah1, bl1, a11, 0, 0, 0);
      a11 = __builtin_amdgcn_mfma_f32_32x32x16_bf16(al1, bh1, a11, 0, 0, 0);
    }
  }
  int base = k0 + 64;
  int lr = 4 * (l >> 5);
  int lc = l & 31;
  if (rv0 && cv0) rmw_tile(A, base + rt0 * 32 + lr, base + ct0 * 32 + lc, a00);
  if (rv0 && cv1) rmw_tile(A, base + rt0 * 32 + lr, base + (ct0 + 1) * 32 + lc, a01);
  if (rv1 && cv0) rmw_tile(A, base + (rt0 + 1) * 32 + lr, base + ct0 * 32 + lc, a10);
  if (rv1 && cv1) rmw_tile(A, base + (rt0 + 1) * 32 + lr, base + (ct0 + 1) * 32 + lc, a11);
  // fused factor of next diagonal block (corner computed solely by this block's wave 0)
  if (blockIdx.x == 0 && blockIdx.y == 0) {
    __syncthreads();
    for (int idx = tid; idx < 64 * 64; idx += 256) {
      int r = idx >> 6, c = idx & 63;
      Dsh[r * 65 + c] = A[(size_t)(base + r) * NN + base + c];
    }
    __syncthreads();
    factor64_lds(Dsh, tid);
    for (int idx = tid; idx < 64 * 64; idx += 256) {
      int r = idx >> 6, c = idx & 63;
      A[(size_t)(base + r) * NN + base + c] = Dsh[r * 65 + c];
    }
  }
}

// ---------------- reduction ----------------

__global__ void logdet_kernel(const float* __restrict__ Mb, double* __restrict__ dlog) {
  int m = blockIdx.x;
  const float* A = Mb + (size_t)m * NN * NN;
  double s = 0.0;
  for (int i = threadIdx.x; i < NN; i += 256)
    s += (double)logf(fabsf(A[(size_t)i * NN + i]));
  __shared__ double red[256];
  red[threadIdx.x] = s;
  __syncthreads();
  for (int k = 128; k > 0; k >>= 1) {
    if (threadIdx.x < k) red[threadIdx.x] += red[threadIdx.x + k];
    __syncthreads();
  }
  if (threadIdx.x == 0) dlog[m] = red[0];
}

__global__ void final_kernel(const double* __restrict__ dlog, float* __restrict__ out) {
  if (threadIdx.x == 0) {
    double acc = 0.0;
    for (int b = 0; b < NBATCH; ++b) acc += dlog[b] - dlog[NBATCH + b];
    out[0] = (float)(acc * 0.25);
  }
}

// ---------------- launch ----------------

extern "C" void kernel_launch(void* const* d_in, const int* in_sizes, int n_in,
                              void* d_out, int out_size, void* d_ws, size_t ws_size,
                              hipStream_t stream) {
  const float* scores  = (const float*)d_in[0];
  const float* tm      = (const float*)d_in[1];
  const float* zm      = (const float*)d_in[2];
  const int*   lengths = (const int*)d_in[3];
  float* out = (float*)d_out;

  char* p = (char*)d_ws;
  float* M = (float*)p;            p += (size_t)NMAT * NN * NN * sizeof(float);
  short* Ahi = (short*)p;          p += (size_t)NMAT * PFRAG * sizeof(short);
  short* Alo = (short*)p;          p += (size_t)NMAT * PFRAG * sizeof(short);
  short* Bhi = (short*)p;          p += (size_t)NMAT * PFRAG * sizeof(short);
  short* Blo = (short*)p;          p += (size_t)NMAT * PFRAG * sizeof(short);
  float* cs = (float*)p;           p += (size_t)NMAT * NN * sizeof(float);
  double* dlog = (double*)p;

  init_cs_kernel<<<(NMAT * NN + 255) / 256, 256, 0, stream>>>(cs);
  build_kernel<<<dim3((NN + 255) / 256, NN / 16, NBATCH), 256, 0, stream>>>(
      scores, zm, tm, lengths, M, cs);
  diag_fix_kernel<<<dim3((NN + 255) / 256, NMAT), 256, 0, stream>>>(
      scores, zm, tm, lengths, cs, M);
  factor_diag<<<NMAT, 256, 0, stream>>>(M, 0);

  for (int k0 = 0; k0 < NN - 64; k0 += 64) {
    int rem = NN - k0 - 64;
    int nt = (rem + 127) / 128;
    panel_solve<<<dim3(nt, NMAT, 2), 128, 0, stream>>>(M, Ahi, Alo, Bhi, Blo, k0);
    trail_gemm<<<dim3(nt, nt, NMAT), 256, 0, stream>>>(M, Ahi, Alo, Bhi, Blo, k0);
  }

  logdet_kernel<<<NMAT, 256, 0, stream>>>(M, dlog);
  final_kernel<<<1, 64, 0, stream>>>(dlog, out);
}